// Round 9
// baseline (141.416 us; speedup 1.0000x reference)
//
#include <hip/hip_runtime.h>
#include <hip/hip_bf16.h>
#include <math.h>

#define N_IMG 8192
#define M_TXT 8192
#define DIMK  256
#define BT    128    // output tile (BT x BT)
#define BK    32     // K-step
#define GRID  ((N_IMG / BT) * (M_TXT / BT))   // 4096

typedef short bf16x8 __attribute__((ext_vector_type(8)));
typedef float f32x4  __attribute__((ext_vector_type(4)));

__device__ inline void gload_lds16(const void* g, void* l) {
    __builtin_amdgcn_global_load_lds(
        (const __attribute__((address_space(1))) unsigned int*)g,
        (__attribute__((address_space(3))) unsigned int*)l,
        16, 0, 0);
}

// RNE fp32 -> bf16 (inputs finite, |x|<=1 -> no NaN handling needed)
__device__ inline unsigned short f2bf(float x) {
    unsigned u = __float_as_uint(x);
    u += 0x7FFFu + ((u >> 16) & 1u);
    return (unsigned short)(u >> 16);
}

// fp32 -> bf16 with the LDS anti-bank-conflict rotation PRE-APPLIED at the
// global level (global_load_lds writes LDS linearly -> permutation must live
// in the source). K-blocks of 32 elems = 4 chunks of 8 bf16; physical chunk j
// of row r holds logical chunk (j - (r>>1)) & 3. Read side uses slot
// (kg + (r16>>1)) & 3 with kg = lane>>4: HW-verified 0 conflicts (slot offset
// MUST vary at lane>>4 granularity; a lane>>5-only variant measured 4.19M
// conflict cycles). Block 0 also zeroes accums and the done counter.
__global__ void convert_swz(const float* __restrict__ srcA,
                            const float* __restrict__ srcB,
                            unsigned short* __restrict__ dstA,
                            unsigned short* __restrict__ dstB,
                            double* __restrict__ accums,
                            int* __restrict__ ctl) {
    if (blockIdx.x == 0) {
#pragma unroll
        for (int s = 0; s < 8; ++s) accums[threadIdx.x * 8 + s] = 0.0;
        if (threadIdx.x == 0) ctl[0] = 0;            // done counter
    }
    int q = blockIdx.x * blockDim.x + threadIdx.x;
    const int per = N_IMG * (DIMK / 8);
    const float* src; unsigned short* dst; int qq = q;
    if (q < per) { src = srcA; dst = dstA; }
    else         { src = srcB; dst = dstB; qq = q - per; }
    int r  = qq >> 5, jj = qq & 31;          // 32 chunks per row
    int kb = jj >> 2, j = jj & 3;            // K-block (32 elems), chunk in block
    int c  = (j - (r >> 1)) & 3;             // logical chunk stored here
    const float4* s = (const float4*)(src + (size_t)r * DIMK + kb * 32 + c * 8);
    float4 a = s[0], b = s[1];
    uint4 w;
    w.x = (unsigned)f2bf(a.x) | ((unsigned)f2bf(a.y) << 16);
    w.y = (unsigned)f2bf(a.z) | ((unsigned)f2bf(a.w) << 16);
    w.z = (unsigned)f2bf(b.x) | ((unsigned)f2bf(b.y) << 16);
    w.w = (unsigned)f2bf(b.z) | ((unsigned)f2bf(b.w) << 16);
    ((uint4*)dst)[qq] = w;
}

// Fused NT GEMM (img @ text^T) + multi-similarity masked reduction.
// EXACT round-3 proven core (session-best 67.3 us GEMM / 75.6 us total):
// 128x128 tile, 4 waves (2Mx2N), 16x16x32 MFMA, BK=32, double-buffered LDS
// (32 KB), 2 barriers + counted vmcnt per K-step, 0 bank conflicts.
// Rounds 4-8 falsified every structural alternative (chain, 256^2 coarse
// phases, whole-K LDS, tickets): each lost 25-86 us to occupancy/diversity/
// spill. Per m233, this 2-phase structure's remaining stall is the
// stage+vmcnt+barrier cadence itself; breaking it requires the full 8-phase
// co-designed schedule, not reachable incrementally from here.
// Only delta vs round-3: finalize fused via done-counter (r8-validated
// ACQ_REL agent-scope pattern) -> one launch removed.
__launch_bounds__(256, 4)
__global__ void msloss_gemm(const unsigned short* __restrict__ Abf,
                            const unsigned short* __restrict__ Bbf,
                            const int* __restrict__ rowLab,
                            const int* __restrict__ colLab,
                            double* __restrict__ accums,
                            int* __restrict__ ctl,
                            float* __restrict__ out) {
    __shared__ __align__(16) unsigned short As[2][BT * BK];   // 8 KB each
    __shared__ __align__(16) unsigned short Bs[2][BT * BK];

    int tid  = threadIdx.x;
    int wave = tid >> 6, lane = tid & 63;
    int r16  = lane & 15, kg = lane >> 4;
    int wrow = (wave >> 1) * 64, wcol = (wave & 1) * 64;

    // bijective XCD swizzle (4096 blocks, 8 XCDs); within an XCD consecutive
    // blocks walk J at fixed I -> A-panel L2 reuse.
    int bid = blockIdx.x;
    int swz = (bid & 7) * 512 + (bid >> 3);
    int tileRow = (swz >> 6) * BT;
    int tileCol = (swz & 63) * BT;

    // Preload labels (8 VMEM ops, retired by iter-0's vmcnt(4); in-order).
    int tr = tileRow + wrow, tc = tileCol + wcol;
    int4 rl4[4]; int mycl[4];
#pragma unroll
    for (int m = 0; m < 4; ++m)
        rl4[m] = *(const int4*)(rowLab + tr + m * 16 + kg * 4);
#pragma unroll
    for (int n = 0; n < 4; ++n)
        mycl[n] = colLab[tc + n * 16 + r16];

    auto STAGE = [&](int sel, int k0) {
#pragma unroll
        for (int i = 0; i < 2; ++i) {
            int p = wave * 128 + i * 64 + lane;      // chunk id 0..511
            int r = p >> 2, j = p & 3;
            gload_lds16(Abf + (size_t)(tileRow + r) * DIMK + k0 + j * 8,
                        &As[sel][(wave * 128 + i * 64) * 8]);
        }
#pragma unroll
        for (int i = 0; i < 2; ++i) {
            int p = wave * 128 + i * 64 + lane;
            int r = p >> 2, j = p & 3;
            gload_lds16(Bbf + (size_t)(tileCol + r) * DIMK + k0 + j * 8,
                        &Bs[sel][(wave * 128 + i * 64) * 8]);
        }
    };

    f32x4 acc[4][4] = {};

    STAGE(0, 0);

#pragma unroll 1
    for (int t = 0; t < DIMK / BK; ++t) {
        if (t < DIMK / BK - 1) {
            STAGE((t + 1) & 1, (t + 1) * BK);        // 4 loads/lane in flight
            asm volatile("s_waitcnt vmcnt(4)" ::: "memory");  // my stage t done
        } else {
            asm volatile("s_waitcnt vmcnt(0)" ::: "memory");
        }
        __builtin_amdgcn_s_barrier();                // all waves' stage t done
        __builtin_amdgcn_sched_barrier(0);

        const unsigned short* as = As[t & 1];
        const unsigned short* bs = Bs[t & 1];
        int slot = ((r16 >> 1) + kg) & 3;
        bf16x8 a[4], b[4];
#pragma unroll
        for (int m = 0; m < 4; ++m)
            a[m] = *(const bf16x8*)(as + (wrow + m * 16 + r16) * BK + slot * 8);
#pragma unroll
        for (int n = 0; n < 4; ++n)
            b[n] = *(const bf16x8*)(bs + (wcol + n * 16 + r16) * BK + slot * 8);
#pragma unroll
        for (int m = 0; m < 4; ++m)
#pragma unroll
            for (int n = 0; n < 4; ++n)
                acc[m][n] = __builtin_amdgcn_mfma_f32_16x16x32_bf16(
                    a[m], b[n], acc[m][n], 0, 0, 0);

        asm volatile("s_waitcnt lgkmcnt(0)" ::: "memory");   // reads of buf done
        __builtin_amdgcn_sched_barrier(0);
        __builtin_amdgcn_s_barrier();
    }

    // ---- fused epilogue (C/D map: col = lane&15, row = kg*4 + reg) ----
    const float CPOS = -2.8853900817779268f;   //  -2 * log2(e)
    const float CNEG = 57.707801635558536f;    //  40 * log2(e)
    const float DPOS = 1.4426950408889634f;    // -0.5*CPOS
    const float DNEG = -28.853900817779268f;   // -0.5*CNEG
    const float THI  = 0.25f;  // skip thresh: dropped terms <= e^-10 each

    float ps = 0.f, ns = 0.f;
    unsigned posc = 0, pec = 0;                // wave-uniform (SALU) counters
#pragma unroll
    for (int m = 0; m < 4; ++m) {
        int lab[4] = {rl4[m].x, rl4[m].y, rl4[m].z, rl4[m].w};
#pragma unroll
        for (int j = 0; j < 4; ++j) {
            int myrl = lab[j];
#pragma unroll
            for (int n = 0; n < 4; ++n) {
                float v  = acc[m][n][j];
                bool eq  = (myrl == mycl[n]);
                bool pos = v > 0.f;
                unsigned long long bp  = __ballot(pos);
                unsigned long long bpe = bp & __ballot(eq);
                unsigned long long bhi = __ballot(v > THI);
                posc += (unsigned)__popcll(bp);    // SALU
                pec  += (unsigned)__popcll(bpe);   // SALU
                if (__builtin_expect((bool)(bpe | bhi), 0)) {
                    float targ = fmaf(v, eq ? CPOS : CNEG, eq ? DPOS : DNEG);
                    float e    = exp2f(pos ? targ : -100.f);  // !pos -> ~0
                    bool  pe   = pos && eq;
                    ps += pe ? e : 0.f;
                    ns += pe ? 0.f : e;            // !pos lanes add ~0
                }
            }
        }
    }
    // wave reduce (64 lanes) — only the two float sums; counts are uniform
#pragma unroll
    for (int off = 32; off > 0; off >>= 1) {
        ps += __shfl_down(ps, off, 64);
        ns += __shfl_down(ns, off, 64);
    }
    if (lane == 0) {
        double* s = accums + ((((unsigned)bid << 2) | (unsigned)wave) & 255u) * 8;
        atomicAdd(s + 0, (double)ps);
        atomicAdd(s + 1, (double)ns);
        atomicAdd((unsigned long long*)(s + 2), (unsigned long long)pec);
        atomicAdd((unsigned long long*)(s + 3), (unsigned long long)(posc - pec));
    }

    // ---- last-done block runs the final reduction inline (r8-validated) ----
    asm volatile("s_waitcnt vmcnt(0)" ::: "memory");   // my atomics retired
    __builtin_amdgcn_s_barrier();                      // all 4 waves' atomics
    if (wave == 0) {
        int old = 0;
        if (lane == 0)
            old = __hip_atomic_fetch_add(ctl, 1, __ATOMIC_ACQ_REL,
                                         __HIP_MEMORY_SCOPE_AGENT);
        old = __shfl(old, 0, 64);
        if (old == GRID - 1) {
            double fps = 0, fns = 0, fpc = 0, fnc = 0;
#pragma unroll
            for (int s = lane; s < 256; s += 64) {
                fps += __hip_atomic_load(&accums[s * 8 + 0], __ATOMIC_RELAXED,
                                         __HIP_MEMORY_SCOPE_AGENT);
                fns += __hip_atomic_load(&accums[s * 8 + 1], __ATOMIC_RELAXED,
                                         __HIP_MEMORY_SCOPE_AGENT);
                fpc += (double)__hip_atomic_load(
                    (unsigned long long*)&accums[s * 8 + 2], __ATOMIC_RELAXED,
                    __HIP_MEMORY_SCOPE_AGENT);
                fnc += (double)__hip_atomic_load(
                    (unsigned long long*)&accums[s * 8 + 3], __ATOMIC_RELAXED,
                    __HIP_MEMORY_SCOPE_AGENT);
            }
#pragma unroll
            for (int off = 32; off > 0; off >>= 1) {
                fps += __shfl_down(fps, off, 64);
                fns += __shfl_down(fns, off, 64);
                fpc += __shfl_down(fpc, off, 64);
                fnc += __shfl_down(fnc, off, 64);
            }
            if (lane == 0) {
                double pl = (fpc > 0.0) ? log1p(fps) / (2.0 * fpc)  : 0.0;
                double nl = (fnc > 0.0) ? log1p(fns) / (40.0 * fnc) : 0.0;
                out[0] = (float)(pl + nl);
            }
        }
    }
}

extern "C" void kernel_launch(void* const* d_in, const int* in_sizes, int n_in,
                              void* d_out, int out_size, void* d_ws, size_t ws_size,
                              hipStream_t stream) {
    (void)in_sizes; (void)n_in; (void)out_size;
    const float* img    = (const float*)d_in[0];
    const float* txt    = (const float*)d_in[1];
    const int*   gt_pre = (const int*)d_in[2];
    const int*   gt_map = (const int*)d_in[3];
    float* out = (float*)d_out;

    const size_t ACC_BYTES = 256 * 8 * sizeof(double);   // 16 KB, 64B slots
    const size_t CTL_BYTES = 256;                        // done counter
    const size_t MAT_BYTES = (size_t)N_IMG * DIMK * 2;   // 4 MB each
    if (ws_size < ACC_BYTES + CTL_BYTES + 2 * MAT_BYTES) return;

    double* accums = (double*)d_ws;
    int*    ctl    = (int*)((char*)d_ws + ACC_BYTES);
    unsigned short* Abf = (unsigned short*)((char*)d_ws + ACC_BYTES + CTL_BYTES);
    unsigned short* Bbf = (unsigned short*)((char*)d_ws + ACC_BYTES + CTL_BYTES + MAT_BYTES);

    int nchunks = 2 * N_IMG * (DIMK / 8);
    convert_swz<<<nchunks / 256, 256, 0, stream>>>(img, txt, Abf, Bbf, accums, ctl);
    msloss_gemm<<<GRID, 256, 0, stream>>>(Abf, Bbf, gt_pre, gt_map, accums, ctl, out);
}

// Round 10
// 75.363 us; speedup vs baseline: 1.8765x; 1.8765x over previous
//
#include <hip/hip_runtime.h>
#include <hip/hip_bf16.h>
#include <math.h>

#define N_IMG 8192
#define M_TXT 8192
#define DIMK  256
#define BT    128    // output tile (BT x BT)
#define BK    32     // K-step

typedef short bf16x8 __attribute__((ext_vector_type(8)));
typedef float f32x4  __attribute__((ext_vector_type(4)));

__device__ inline void gload_lds16(const void* g, void* l) {
    __builtin_amdgcn_global_load_lds(
        (const __attribute__((address_space(1))) unsigned int*)g,
        (__attribute__((address_space(3))) unsigned int*)l,
        16, 0, 0);
}

// RNE fp32 -> bf16 (inputs finite, |x|<=1 -> no NaN handling needed)
__device__ inline unsigned short f2bf(float x) {
    unsigned u = __float_as_uint(x);
    u += 0x7FFFu + ((u >> 16) & 1u);
    return (unsigned short)(u >> 16);
}

// fp32 -> bf16 with the LDS anti-bank-conflict rotation PRE-APPLIED at the
// global level (global_load_lds writes LDS linearly -> permutation must live
// in the source). K-blocks of 32 elems = 4 chunks of 8 bf16; physical chunk j
// of row r holds logical chunk (j - (r>>1)) & 3. Read side uses slot
// (kg + (r16>>1)) & 3 with kg = lane>>4: HW-verified 0 conflicts (slot offset
// MUST vary at lane>>4 granularity; a lane>>5-only variant measured 4.19M
// conflict cycles). Block 0 also zeroes the accumulators.
__global__ void convert_swz(const float* __restrict__ srcA,
                            const float* __restrict__ srcB,
                            unsigned short* __restrict__ dstA,
                            unsigned short* __restrict__ dstB,
                            double* __restrict__ accums) {
    if (blockIdx.x == 0) {
#pragma unroll
        for (int s = 0; s < 8; ++s) accums[threadIdx.x * 8 + s] = 0.0;
    }
    int q = blockIdx.x * blockDim.x + threadIdx.x;
    const int per = N_IMG * (DIMK / 8);
    const float* src; unsigned short* dst; int qq = q;
    if (q < per) { src = srcA; dst = dstA; }
    else         { src = srcB; dst = dstB; qq = q - per; }
    int r  = qq >> 5, jj = qq & 31;          // 32 chunks per row
    int kb = jj >> 2, j = jj & 3;            // K-block (32 elems), chunk in block
    int c  = (j - (r >> 1)) & 3;             // logical chunk stored here
    const float4* s = (const float4*)(src + (size_t)r * DIMK + kb * 32 + c * 8);
    float4 a = s[0], b = s[1];
    uint4 w;
    w.x = (unsigned)f2bf(a.x) | ((unsigned)f2bf(a.y) << 16);
    w.y = (unsigned)f2bf(a.z) | ((unsigned)f2bf(a.w) << 16);
    w.z = (unsigned)f2bf(b.x) | ((unsigned)f2bf(b.y) << 16);
    w.w = (unsigned)f2bf(b.z) | ((unsigned)f2bf(b.w) << 16);
    ((uint4*)dst)[qq] = w;
}

// Fused NT GEMM (img @ text^T) + multi-similarity masked reduction.
// SESSION-BEST configuration (round 3: 67.3 us GEMM / 75.58 us total),
// restored byte-for-byte after rounds 4-9 falsified every structural
// alternative with counter-isolated causes:
//   r1 32x32 frag rotation -> 4.19M bank-conflict cycles (+8 us)
//   r2 triple-buffer 48KB  -> LDS granularity cost a block (+5 us)
//   r4 chained tiles       -> grid quantization, solo generations (+26 us)
//   r5/r6/r7 coarse phases -> 1-2 waves/SIMD latency exposure (+25-86 us)
//   r8 ticket persistence  -> in-loop sync + lost phase diversity (+25 us)
//   r9 fused finalize      -> per-block agent-scope ACQ_REL atomic = device-
//                             wide L2 invalidate storm (2x slowdown)
// Core: 128x128 tile, 4 waves (2Mx2N), 16x16x32 MFMA, BK=32, double-buffered
// LDS (32 KB), 2 barriers + counted vmcnt(4) per K-step, 0 bank conflicts.
// Residual stall is the 2-phase stage+vmcnt+barrier cadence (m233 regime);
// escaping it needs the full co-designed 8-phase schedule, not reachable
// incrementally (three partial reconstructions all landed at 14% MfmaUtil).
__launch_bounds__(256, 4)
__global__ void msloss_gemm(const unsigned short* __restrict__ Abf,
                            const unsigned short* __restrict__ Bbf,
                            const int* __restrict__ rowLab,
                            const int* __restrict__ colLab,
                            double* __restrict__ accums) {
    __shared__ __align__(16) unsigned short As[2][BT * BK];   // 8 KB each
    __shared__ __align__(16) unsigned short Bs[2][BT * BK];

    int tid  = threadIdx.x;
    int wave = tid >> 6, lane = tid & 63;
    int r16  = lane & 15, kg = lane >> 4;
    int wrow = (wave >> 1) * 64, wcol = (wave & 1) * 64;

    // bijective XCD swizzle (4096 blocks, 8 XCDs); within an XCD consecutive
    // blocks walk J at fixed I -> A-panel L2 reuse.
    int bid = blockIdx.x;
    int swz = (bid & 7) * 512 + (bid >> 3);
    int tileRow = (swz >> 6) * BT;
    int tileCol = (swz & 63) * BT;

    // Preload labels (8 VMEM ops, retired by iter-0's vmcnt(4); in-order).
    int tr = tileRow + wrow, tc = tileCol + wcol;
    int4 rl4[4]; int mycl[4];
#pragma unroll
    for (int m = 0; m < 4; ++m)
        rl4[m] = *(const int4*)(rowLab + tr + m * 16 + kg * 4);
#pragma unroll
    for (int n = 0; n < 4; ++n)
        mycl[n] = colLab[tc + n * 16 + r16];

    auto STAGE = [&](int sel, int k0) {
#pragma unroll
        for (int i = 0; i < 2; ++i) {
            int p = wave * 128 + i * 64 + lane;      // chunk id 0..511
            int r = p >> 2, j = p & 3;
            gload_lds16(Abf + (size_t)(tileRow + r) * DIMK + k0 + j * 8,
                        &As[sel][(wave * 128 + i * 64) * 8]);
        }
#pragma unroll
        for (int i = 0; i < 2; ++i) {
            int p = wave * 128 + i * 64 + lane;
            int r = p >> 2, j = p & 3;
            gload_lds16(Bbf + (size_t)(tileCol + r) * DIMK + k0 + j * 8,
                        &Bs[sel][(wave * 128 + i * 64) * 8]);
        }
    };

    f32x4 acc[4][4] = {};

    STAGE(0, 0);

#pragma unroll 1
    for (int t = 0; t < DIMK / BK; ++t) {
        if (t < DIMK / BK - 1) {
            STAGE((t + 1) & 1, (t + 1) * BK);        // 4 loads/lane in flight
            asm volatile("s_waitcnt vmcnt(4)" ::: "memory");  // my stage t done
        } else {
            asm volatile("s_waitcnt vmcnt(0)" ::: "memory");
        }
        __builtin_amdgcn_s_barrier();                // all waves' stage t done
        __builtin_amdgcn_sched_barrier(0);

        const unsigned short* as = As[t & 1];
        const unsigned short* bs = Bs[t & 1];
        int slot = ((r16 >> 1) + kg) & 3;
        bf16x8 a[4], b[4];
#pragma unroll
        for (int m = 0; m < 4; ++m)
            a[m] = *(const bf16x8*)(as + (wrow + m * 16 + r16) * BK + slot * 8);
#pragma unroll
        for (int n = 0; n < 4; ++n)
            b[n] = *(const bf16x8*)(bs + (wcol + n * 16 + r16) * BK + slot * 8);
#pragma unroll
        for (int m = 0; m < 4; ++m)
#pragma unroll
            for (int n = 0; n < 4; ++n)
                acc[m][n] = __builtin_amdgcn_mfma_f32_16x16x32_bf16(
                    a[m], b[n], acc[m][n], 0, 0, 0);

        asm volatile("s_waitcnt lgkmcnt(0)" ::: "memory");   // reads of buf done
        __builtin_amdgcn_sched_barrier(0);
        __builtin_amdgcn_s_barrier();
    }

    // ---- fused epilogue (C/D map: col = lane&15, row = kg*4 + reg) ----
    const float CPOS = -2.8853900817779268f;   //  -2 * log2(e)
    const float CNEG = 57.707801635558536f;    //  40 * log2(e)
    const float DPOS = 1.4426950408889634f;    // -0.5*CPOS
    const float DNEG = -28.853900817779268f;   // -0.5*CNEG
    const float THI  = 0.25f;  // skip thresh: dropped terms <= e^-10 each

    float ps = 0.f, ns = 0.f;
    unsigned posc = 0, pec = 0;                // wave-uniform (SALU) counters
#pragma unroll
    for (int m = 0; m < 4; ++m) {
        int lab[4] = {rl4[m].x, rl4[m].y, rl4[m].z, rl4[m].w};
#pragma unroll
        for (int j = 0; j < 4; ++j) {
            int myrl = lab[j];
#pragma unroll
            for (int n = 0; n < 4; ++n) {
                float v  = acc[m][n][j];
                bool eq  = (myrl == mycl[n]);
                bool pos = v > 0.f;
                unsigned long long bp  = __ballot(pos);
                unsigned long long bpe = bp & __ballot(eq);
                unsigned long long bhi = __ballot(v > THI);
                posc += (unsigned)__popcll(bp);    // SALU
                pec  += (unsigned)__popcll(bpe);   // SALU
                if (__builtin_expect((bool)(bpe | bhi), 0)) {
                    float targ = fmaf(v, eq ? CPOS : CNEG, eq ? DPOS : DNEG);
                    float e    = exp2f(pos ? targ : -100.f);  // !pos -> ~0
                    bool  pe   = pos && eq;
                    ps += pe ? e : 0.f;
                    ns += pe ? 0.f : e;            // !pos lanes add ~0
                }
            }
        }
    }
    // wave reduce (64 lanes) — only the two float sums; counts are uniform
#pragma unroll
    for (int off = 32; off > 0; off >>= 1) {
        ps += __shfl_down(ps, off, 64);
        ns += __shfl_down(ns, off, 64);
    }
    if (lane == 0) {
        double* s = accums + ((((unsigned)bid << 2) | (unsigned)wave) & 255u) * 8;
        atomicAdd(s + 0, (double)ps);
        atomicAdd(s + 1, (double)ns);
        atomicAdd((unsigned long long*)(s + 2), (unsigned long long)pec);
        atomicAdd((unsigned long long*)(s + 3), (unsigned long long)(posc - pec));
    }
}

__global__ void finalize_loss(const double* __restrict__ accums,
                              float* __restrict__ out) {
    int lane = threadIdx.x;
    double ps = 0, ns = 0, pc = 0, nc = 0;
#pragma unroll
    for (int s = lane; s < 256; s += 64) {
        ps += accums[s * 8 + 0];
        ns += accums[s * 8 + 1];
        pc += (double)((const unsigned long long*)accums)[s * 8 + 2];
        nc += (double)((const unsigned long long*)accums)[s * 8 + 3];
    }
#pragma unroll
    for (int off = 32; off > 0; off >>= 1) {
        ps += __shfl_down(ps, off, 64);
        ns += __shfl_down(ns, off, 64);
        pc += __shfl_down(pc, off, 64);
        nc += __shfl_down(nc, off, 64);
    }
    if (lane == 0) {
        double pl = (pc > 0.0) ? log1p(ps) / (2.0 * pc)  : 0.0;
        double nl = (nc > 0.0) ? log1p(ns) / (40.0 * nc) : 0.0;
        out[0] = (float)(pl + nl);
    }
}

extern "C" void kernel_launch(void* const* d_in, const int* in_sizes, int n_in,
                              void* d_out, int out_size, void* d_ws, size_t ws_size,
                              hipStream_t stream) {
    (void)in_sizes; (void)n_in; (void)out_size;
    const float* img    = (const float*)d_in[0];
    const float* txt    = (const float*)d_in[1];
    const int*   gt_pre = (const int*)d_in[2];
    const int*   gt_map = (const int*)d_in[3];
    float* out = (float*)d_out;

    const size_t ACC_BYTES = 256 * 8 * sizeof(double);   // 16 KB, 64B slots
    const size_t MAT_BYTES = (size_t)N_IMG * DIMK * 2;   // 4 MB each
    if (ws_size < ACC_BYTES + 2 * MAT_BYTES) return;

    double*         accums = (double*)d_ws;
    unsigned short* Abf = (unsigned short*)((char*)d_ws + ACC_BYTES);
    unsigned short* Bbf = (unsigned short*)((char*)d_ws + ACC_BYTES + MAT_BYTES);

    int nchunks = 2 * N_IMG * (DIMK / 8);
    convert_swz<<<nchunks / 256, 256, 0, stream>>>(img, txt, Abf, Bbf, accums);
    msloss_gemm<<<(N_IMG / BT) * (M_TXT / BT), 256, 0, stream>>>(Abf, Bbf, gt_pre, gt_map, accums);
    finalize_loss<<<1, 64, 0, stream>>>(accums, out);
}